// Round 12
// baseline (3991.207 us; speedup 1.0000x reference)
//
#include <hip/hip_runtime.h>

constexpr int kB = 256;
constexpr int kS = 512;
constexpr int kU = 256;

typedef _Float16 f16x2 __attribute__((ext_vector_type(2)));
typedef _Float16 f16x8 __attribute__((ext_vector_type(8)));
typedef float    f32x4 __attribute__((ext_vector_type(4)));
typedef unsigned u32x4 __attribute__((ext_vector_type(4)));

// fast activations: v_rcp-based. ~1 ulp rcp error, negligible vs fp16 quantum.
__device__ __forceinline__ float sigm(float x) {
    return __builtin_amdgcn_rcpf(1.0f + __expf(-x));
}
__device__ __forceinline__ float tanh_fast(float x) {
    const float ex = __expf(2.0f * x);
    return 1.0f - 2.0f * __builtin_amdgcn_rcpf(ex + 1.0f);
}
__device__ __forceinline__ unsigned packh2(float lo, float hi) {
    f16x2 h; h.x = (_Float16)lo; h.y = (_Float16)hi;
    return __builtin_bit_cast(unsigned, h);
}
// frag-linear 16x256 fp16 A-tile with XOR bank swizzle (applied uniformly at
// write(afrag_byte) and read(ard): byte ^= ((byte>>8)&3)<<4 — involution on
// bits>=4, keeps 16B reads contiguous, breaks the 8-way write-bank alias).
__device__ __forceinline__ int afrag_byte(int m, int k) {
    const int b = (k >> 5) * 1024 + ((m & 15) + 16 * ((k >> 3) & 3)) * 16 + (k & 7) * 2;
    return b ^ (((b >> 8) & 3) << 4);
}
__device__ __forceinline__ int ard(int kt, int lane) {
    const int b = kt * 1024 + lane * 16;
    return b ^ (((b >> 8) & 3) << 4);
}

// ---------------------------------------------------------------------------
// ws: uint4 B-frag weights for all 7 matrices, PERMUTED column order:
//   idx = mat*8192 + (nt*8 + kt)*64 + lane
//   lane l in tile nt holds TRUE column n = 32*(nt>>1) + 2*(l&15) + (nt&1)
//   mats: 0=hU 1=fW 2=iW 3=cW 4=oW 5=tW 6=yW
// ---------------------------------------------------------------------------
__global__ __launch_bounds__(256) void convert_frag(
    const float* __restrict__ hU, const float* __restrict__ fW,
    const float* __restrict__ iW, const float* __restrict__ cW,
    const float* __restrict__ oW, const float* __restrict__ tW,
    const float* __restrict__ yW, uint4* __restrict__ wfrag)
{
    const int idx = blockIdx.x * 256 + threadIdx.x;   // 7*8192
    const int mat = idx >> 13;
    const int r   = idx & 8191;
    const int lane = r & 63;
    const int kt   = (r >> 6) & 7;
    const int nt   = r >> 9;
    const float* W = mat == 0 ? hU : mat == 1 ? fW : mat == 2 ? iW :
                     mat == 3 ? cW : mat == 4 ? oW : mat == 5 ? tW : yW;
    const int n  = 32 * (nt >> 1) + 2 * (lane & 15) + (nt & 1);
    const int k0 = kt * 32 + 8 * (lane >> 4);
    uint4 u;
    u.x = packh2(W[(k0 + 0) * kU + n], W[(k0 + 1) * kU + n]);
    u.y = packh2(W[(k0 + 2) * kU + n], W[(k0 + 3) * kU + n]);
    u.z = packh2(W[(k0 + 4) * kU + n], W[(k0 + 5) * kU + n]);
    u.w = packh2(W[(k0 + 6) * kU + n], W[(k0 + 7) * kU + n]);
    wfrag[idx] = u;
}

// ---------------------------------------------------------------------------
// Phase 1: sequential recurrence, weight-resident, all-VGPR pins.
// 16 blocks x 256 threads (4 waves, 1/SIMD, 512 regs/wave).
// Wave w owns tiles 4w..4w+3 = true cols cA=64w+2*m16(+1), cB=cA+32(+1).
// hU in LDS (128 KB); fW,iW pinned VGPR (256); cW un-pinned (compiler keeps
// ~64 regs or streams from idle VMEM pipe — both acceptable).
// h/h1 in swizzled frag-linear LDS A-tiles; 2 barriers/step. No oW here.
// Output: packed u32 (h fp16 lo | h1 fp16 hi), 2x uint2 per lane per row.
// ---------------------------------------------------------------------------

#define MFMA16(A, W, Acc) __builtin_amdgcn_mfma_f32_16x16x32_f16( \
    (A), __builtin_bit_cast(f16x8, (W)), (Acc), 0, 0, 0)

#define LOADW8(pre, moff, nt)                                       \
  u32x4 pre##_0 = wfragv[(moff) + ((nt)*8+0)*64 + lane];            \
  u32x4 pre##_1 = wfragv[(moff) + ((nt)*8+1)*64 + lane];            \
  u32x4 pre##_2 = wfragv[(moff) + ((nt)*8+2)*64 + lane];            \
  u32x4 pre##_3 = wfragv[(moff) + ((nt)*8+3)*64 + lane];            \
  u32x4 pre##_4 = wfragv[(moff) + ((nt)*8+4)*64 + lane];            \
  u32x4 pre##_5 = wfragv[(moff) + ((nt)*8+5)*64 + lane];            \
  u32x4 pre##_6 = wfragv[(moff) + ((nt)*8+6)*64 + lane];            \
  u32x4 pre##_7 = wfragv[(moff) + ((nt)*8+7)*64 + lane];

#define PINV8(pre) asm volatile("" : "+v"(pre##_0), "+v"(pre##_1),  \
  "+v"(pre##_2), "+v"(pre##_3), "+v"(pre##_4), "+v"(pre##_5),       \
  "+v"(pre##_6), "+v"(pre##_7));

#define GATE_KT(kt) {                                               \
  const f16x8 A = *(const f16x8*)(hAb + ard(kt, lane));             \
  F0 = MFMA16(A, wfA_##kt, F0);                                     \
  F1 = MFMA16(A, wfB_##kt, F1);                                     \
  F2 = MFMA16(A, wfC_##kt, F2);                                     \
  F3 = MFMA16(A, wfD_##kt, F3);                                     \
  I0 = MFMA16(A, wiA_##kt, I0);                                     \
  I1 = MFMA16(A, wiB_##kt, I1);                                     \
  I2 = MFMA16(A, wiC_##kt, I2);                                     \
  I3 = MFMA16(A, wiD_##kt, I3);                                     \
  C0 = MFMA16(A, cw0[kt], C0);                                      \
  C1 = MFMA16(A, cw1[kt], C1);                                      \
  C2 = MFMA16(A, cw2[kt], C2);                                      \
  C3 = MFMA16(A, cw3[kt], C3); }

__global__ __launch_bounds__(256, 1) void rnn_phase1(
    const int* __restrict__ z,
    const float* __restrict__ hW, const float* __restrict__ hb,
    const float* __restrict__ fb, const float* __restrict__ ib,
    const float* __restrict__ cb,
    const float* __restrict__ h0,
    const uint4* __restrict__ wfrag,
    unsigned* __restrict__ outu)
{
    extern __shared__ __align__(16) char smem[];
    uint4* hUl  = (uint4*)smem;                // 131072 B
    char*  h1Ab = smem + 131072;               // 8192 B
    char*  hAb  = smem + 139264;               // 8192 B

    const int tid  = threadIdx.x;
    const int w    = tid >> 6;                 // 0..3
    const int lane = tid & 63;
    const int m16  = lane & 15;
    const int g    = lane >> 4;
    const int b0   = blockIdx.x * 16;
    const int nt0  = 4 * w, nt1 = nt0 + 1, nt2 = nt0 + 2, nt3 = nt0 + 3;
    const int cA   = 64 * w + 2 * m16;         // true cols cA, cA+1
    const int cB   = cA + 32;                  // true cols cB, cB+1

    const u32x4* wfragv = (const u32x4*)wfrag;

    for (int i = tid; i < 8192; i += 256) hUl[i] = wfrag[i];

    // fW, iW: pinned VGPR (256 regs)
    LOADW8(wfA,  8192, nt0) LOADW8(wfB,  8192, nt1)
    LOADW8(wfC,  8192, nt2) LOADW8(wfD,  8192, nt3)
    LOADW8(wiA, 16384, nt0) LOADW8(wiB, 16384, nt1)
    LOADW8(wiC, 16384, nt2) LOADW8(wiD, 16384, nt3)
    PINV8(wfA) PINV8(wfB) PINV8(wfC) PINV8(wfD)
    PINV8(wiA) PINV8(wiB) PINV8(wiC) PINV8(wiD)

    // cW: un-pinned (compiler keeps in regs or streams; loop-invariant)
    u32x4 cw0[8], cw1[8], cw2[8], cw3[8];
    #pragma unroll
    for (int kt = 0; kt < 8; ++kt) {
        cw0[kt] = wfragv[24576 + (nt0 * 8 + kt) * 64 + lane];
        cw1[kt] = wfragv[24576 + (nt1 * 8 + kt) * 64 + lane];
        cw2[kt] = wfragv[24576 + (nt2 * 8 + kt) * 64 + lane];
        cw3[kt] = wfragv[24576 + (nt3 * 8 + kt) * 64 + lane];
    }

    const float2 hbA = *(const float2*)&hb[cA], hbB = *(const float2*)&hb[cB];
    const float2 fbA = *(const float2*)&fb[cA], fbB = *(const float2*)&fb[cB];
    const float2 ibA = *(const float2*)&ib[cA], ibB = *(const float2*)&ib[cB];
    const float2 cbA = *(const float2*)&cb[cA], cbB = *(const float2*)&cb[cB];

    // h1 master fp32 (rows 4g+r; cols cA, cA+1, cB, cB+1)
    float h1A0[4], h1A1[4], h1B0[4], h1B1[4];
    {
        const float2 hA2 = *(const float2*)&h0[cA];
        const float2 hB2 = *(const float2*)&h0[cB];
        #pragma unroll
        for (int r = 0; r < 4; ++r) {
            h1A0[r] = hA2.x; h1A1[r] = hA2.y;
            h1B0[r] = hB2.x; h1B1[r] = hB2.y;
        }
    }
    // init h1A tile (paired b32 writes, swizzled)
    for (int i = tid; i < 2048; i += 256) {
        const int m = i >> 7, kp = i & 127;
        *(unsigned*)(h1Ab + afrag_byte(m, 2 * kp)) =
            packh2(h0[2 * kp], h0[2 * kp + 1]);
    }
    __syncthreads();

    const unsigned obase = (unsigned)((b0 + 4 * g) * kS) * kU + cA;

    for (int t = 0; t < kS; ++t) {
        // embedding gathers (adjacent true-col float2 pairs)
        float2 eA[4], eB[4];
        #pragma unroll
        for (int r = 0; r < 4; ++r) {
            int zt = 0;
            if (t > 0) zt = z[(b0 + 4 * g + r) * kS + t - 1] + 1;
            const float* hwr = hW + (size_t)zt * kU;
            eA[r] = *(const float2*)&hwr[cA];
            eB[r] = *(const float2*)&hwr[cB];
        }

        // a = h1 @ hU (A from LDS h1A swizzled, B from LDS hU)
        f32x4 a0 = {0.f,0.f,0.f,0.f}, a1 = {0.f,0.f,0.f,0.f};
        f32x4 a2 = {0.f,0.f,0.f,0.f}, a3 = {0.f,0.f,0.f,0.f};
        #pragma unroll
        for (int kt = 0; kt < 8; ++kt) {
            const f16x8 A = *(const f16x8*)(h1Ab + ard(kt, lane));
            a0 = MFMA16(A, hUl[(nt0 * 8 + kt) * 64 + lane], a0);
            a1 = MFMA16(A, hUl[(nt1 * 8 + kt) * 64 + lane], a1);
            a2 = MFMA16(A, hUl[(nt2 * 8 + kt) * 64 + lane], a2);
            a3 = MFMA16(A, hUl[(nt3 * 8 + kt) * 64 + lane], a3);
        }

        // h = tanh(a + emb + hb) -> hA tile + keep in regs
        float hA0[4], hA1[4], hB0[4], hB1[4];
        #pragma unroll
        for (int r = 0; r < 4; ++r) {
            hA0[r] = tanh_fast(a0[r] + eA[r].x + hbA.x);
            hA1[r] = tanh_fast(a1[r] + eA[r].y + hbA.y);
            hB0[r] = tanh_fast(a2[r] + eB[r].x + hbB.x);
            hB1[r] = tanh_fast(a3[r] + eB[r].y + hbB.y);
            *(unsigned*)(hAb + afrag_byte(4 * g + r, cA)) = packh2(hA0[r], hA1[r]);
            *(unsigned*)(hAb + afrag_byte(4 * g + r, cB)) = packh2(hB0[r], hB1[r]);
        }
        __syncthreads();   // barrier 1: hA complete; h1A reads done

        // fused gate pass: F, I, C for 4 tiles
        f32x4 F0={0.f,0.f,0.f,0.f}, F1={0.f,0.f,0.f,0.f};
        f32x4 F2={0.f,0.f,0.f,0.f}, F3={0.f,0.f,0.f,0.f};
        f32x4 I0={0.f,0.f,0.f,0.f}, I1={0.f,0.f,0.f,0.f};
        f32x4 I2={0.f,0.f,0.f,0.f}, I3={0.f,0.f,0.f,0.f};
        f32x4 C0={0.f,0.f,0.f,0.f}, C1={0.f,0.f,0.f,0.f};
        f32x4 C2={0.f,0.f,0.f,0.f}, C3={0.f,0.f,0.f,0.f};
        GATE_KT(0) GATE_KT(1) GATE_KT(2) GATE_KT(3)
        GATE_KT(4) GATE_KT(5) GATE_KT(6) GATE_KT(7)

        // update h1, store packed (h,h1), refresh h1A tile
        const unsigned tOff = (unsigned)t * kU;
        #pragma unroll
        for (int r = 0; r < 4; ++r) {
            const int m = 4 * g + r;
            h1A0[r] = h1A0[r] * sigm(F0[r] + fbA.x)
                    + tanh_fast(C0[r] + cbA.x) * sigm(I0[r] + ibA.x);
            h1A1[r] = h1A1[r] * sigm(F1[r] + fbA.y)
                    + tanh_fast(C1[r] + cbA.y) * sigm(I1[r] + ibA.y);
            h1B0[r] = h1B0[r] * sigm(F2[r] + fbB.x)
                    + tanh_fast(C2[r] + cbB.x) * sigm(I2[r] + ibB.x);
            h1B1[r] = h1B1[r] * sigm(F3[r] + fbB.y)
                    + tanh_fast(C3[r] + cbB.y) * sigm(I3[r] + ibB.y);
            uint2 ovA, ovB;
            ovA.x = packh2(hA0[r], h1A0[r]);  ovA.y = packh2(hA1[r], h1A1[r]);
            ovB.x = packh2(hB0[r], h1B0[r]);  ovB.y = packh2(hB1[r], h1B1[r]);
            const unsigned o = obase + ((unsigned)r << 17) + tOff;
            *(uint2*)&outu[o]      = ovA;
            *(uint2*)&outu[o + 32] = ovB;
            *(unsigned*)(h1Ab + afrag_byte(m, cA)) = packh2(h1A0[r], h1A1[r]);
            *(unsigned*)(h1Ab + afrag_byte(m, cB)) = packh2(h1B0[r], h1B1[r]);
        }
        __syncthreads();   // barrier 2: h1A refreshed
    }
}

// ---------------------------------------------------------------------------
// Phase 2: output head, MFMA. 4096 blocks x 256 threads (4 waves), 32 rows.
// o = sigm(h@oW+ob), g = o*h1, tt = tanh(g@tW+tb), y = softmax(tt@yW+yb).
// ---------------------------------------------------------------------------
#define P2_MATVEC(MOFF)                                                   \
  {                                                                       \
    f16x8 Af[2][8];                                                       \
    _Pragma("unroll") for (int kt = 0; kt < 8; ++kt) {                    \
      Af[0][kt] = *(const f16x8*)(aT + ard(kt, lane));                    \
      Af[1][kt] = *(const f16x8*)(aT + 8192 + ard(kt, lane));             \
    }                                                                     \
    _Pragma("unroll") for (int ntl = 0; ntl < 4; ++ntl) {                 \
      const int nt = 4 * w + ntl;                                         \
      acc[0][ntl] = (f32x4){0.f, 0.f, 0.f, 0.f};                          \
      acc[1][ntl] = (f32x4){0.f, 0.f, 0.f, 0.f};                          \
      _Pragma("unroll") for (int kt = 0; kt < 8; ++kt) {                  \
        const f16x8 Bf = __builtin_bit_cast(f16x8,                        \
            wfrag[(MOFF) + (nt * 8 + kt) * 64 + lane]);                   \
        acc[0][ntl] = __builtin_amdgcn_mfma_f32_16x16x32_f16(             \
            Af[0][kt], Bf, acc[0][ntl], 0, 0, 0);                         \
        acc[1][ntl] = __builtin_amdgcn_mfma_f32_16x16x32_f16(             \
            Af[1][kt], Bf, acc[1][ntl], 0, 0, 0);                         \
      }                                                                   \
    }                                                                     \
  }

__global__ __launch_bounds__(256, 2) void rnn_phase2(
    const float* __restrict__ ob_, const float* __restrict__ tb,
    const float* __restrict__ yb,
    const uint4* __restrict__ wfrag,
    float* __restrict__ out)
{
    extern __shared__ __align__(16) char smem[];
    unsigned* pkl = (unsigned*)smem;           // 32*256 u32 = 32768 B
    char*     aT  = smem + 32768;              // 2 A-tiles = 16384 B
    float*    lg  = (float*)(smem + 49152);    // logits 32768 B

    const int tid  = threadIdx.x;
    const int w    = tid >> 6;
    const int lane = tid & 63;
    const int m16  = lane & 15;
    const int g    = lane >> 4;
    const size_t rowbase = (size_t)blockIdx.x * 32;
    unsigned* outu = (unsigned*)out;

    {
        const uint4* src = (const uint4*)(outu + rowbase * kU);
        uint4* dst = (uint4*)pkl;
        #pragma unroll
        for (int i = 0; i < 8; ++i) dst[i * 256 + tid] = src[i * 256 + tid];
    }
    __syncthreads();

    // build h A-tiles (lo halves, paired b32, swizzled)
    for (int i = tid; i < 4096; i += 256) {
        const int row = i >> 7, kp = i & 127;
        const unsigned p0 = pkl[row * 256 + 2 * kp];
        const unsigned p1 = pkl[row * 256 + 2 * kp + 1];
        *(unsigned*)(aT + (row >> 4) * 8192 + afrag_byte(row & 15, 2 * kp)) =
            (p0 & 0xFFFFu) | (p1 << 16);
    }
    __syncthreads();

    const int cA = 64 * w + 2 * m16;
    const int cB = cA + 32;

    f32x4 acc[2][4];

    // ---- o = sigm(h @ oW + ob); g = o * h1 -> gA tiles ----
    P2_MATVEC(4 * 8192)
    __syncthreads();
    {
        const float2 obA = *(const float2*)&ob_[cA];
        const float2 obB = *(const float2*)&ob_[cB];
        #pragma unroll
        for (int mt = 0; mt < 2; ++mt) {
            #pragma unroll
            for (int r = 0; r < 4; ++r) {
                const int row = mt * 16 + 4 * g + r;
                const f16x2 qA0 = __builtin_bit_cast(f16x2, pkl[row * 256 + cA]);
                const f16x2 qA1 = __builtin_bit_cast(f16x2, pkl[row * 256 + cA + 1]);
                const f16x2 qB0 = __builtin_bit_cast(f16x2, pkl[row * 256 + cB]);
                const f16x2 qB1 = __builtin_bit_cast(f16x2, pkl[row * 256 + cB + 1]);
                const float g0 = sigm(acc[mt][0][r] + obA.x) * (float)qA0.y;
                const float g1 = sigm(acc[mt][1][r] + obA.y) * (float)qA1.y;
                const float g2 = sigm(acc[mt][2][r] + obB.x) * (float)qB0.y;
                const float g3 = sigm(acc[mt][3][r] + obB.y) * (float)qB1.y;
                char* tile = aT + mt * 8192;
                *(unsigned*)(tile + afrag_byte(row & 15, cA)) = packh2(g0, g1);
                *(unsigned*)(tile + afrag_byte(row & 15, cB)) = packh2(g2, g3);
            }
        }
    }
    __syncthreads();

    // ---- tt = tanh(g @ tW + tb) -> ttA tiles ----
    P2_MATVEC(5 * 8192)
    __syncthreads();
    {
        const float2 tbA = *(const float2*)&tb[cA];
        const float2 tbB = *(const float2*)&tb[cB];
        #pragma unroll
        for (int mt = 0; mt < 2; ++mt) {
            #pragma unroll
            for (int r = 0; r < 4; ++r) {
                const int row = mt * 16 + 4 * g + r;
                const float t0 = tanh_fast(acc[mt][0][r] + tbA.x);
                const float t1 = tanh_fast(acc[mt][1][r] + tbA.y);
                const float t2 = tanh_fast(acc[mt][2][r] + tbB.x);
                const float t3 = tanh_fast(acc[mt][3][r] + tbB.y);
                char* tile = aT + mt * 8192;
                *(unsigned*)(tile + afrag_byte(row & 15, cA)) = packh2(t0, t1);
                *(unsigned*)(tile + afrag_byte(row & 15, cB)) = packh2(t2, t3);
            }
        }
    }
    __syncthreads();

    // ---- logits = tt @ yW + yb ----
    P2_MATVEC(6 * 8192)
    {
        const float2 ybA = *(const float2*)&yb[cA];
        const float2 ybB = *(const float2*)&yb[cB];
        #pragma unroll
        for (int mt = 0; mt < 2; ++mt) {
            #pragma unroll
            for (int r = 0; r < 4; ++r) {
                const int row = mt * 16 + 4 * g + r;
                float2 lA, lB;
                lA.x = acc[mt][0][r] + ybA.x;  lA.y = acc[mt][1][r] + ybA.y;
                lB.x = acc[mt][2][r] + ybB.x;  lB.y = acc[mt][3][r] + ybB.y;
                *(float2*)&lg[row * 256 + cA] = lA;
                *(float2*)&lg[row * 256 + cB] = lB;
            }
        }
    }
    __syncthreads();

    for (int q = 0; q < 8; ++q) {
        const int r = w * 8 + q;
        const float4 v = *(const float4*)&lg[r * 256 + lane * 4];
        float m = fmaxf(fmaxf(v.x, v.y), fmaxf(v.z, v.w));
        #pragma unroll
        for (int off = 32; off > 0; off >>= 1) m = fmaxf(m, __shfl_xor(m, off, 64));
        const float e0 = __expf(v.x - m), e1 = __expf(v.y - m);
        const float e2 = __expf(v.z - m), e3 = __expf(v.w - m);
        float s = e0 + e1 + e2 + e3;
        #pragma unroll
        for (int off = 32; off > 0; off >>= 1) s += __shfl_xor(s, off, 64);
        const float inv = 1.0f / s;
        float4 o4; o4.x = e0 * inv; o4.y = e1 * inv; o4.z = e2 * inv; o4.w = e3 * inv;
        *(float4*)&out[(rowbase + r) * kU + lane * 4] = o4;
    }
}

extern "C" void kernel_launch(void* const* d_in, const int* in_sizes, int n_in,
                              void* d_out, int out_size, void* d_ws, size_t ws_size,
                              hipStream_t stream) {
    const int*   z  = (const int*)d_in[0];
    const float* hW = (const float*)d_in[1];
    const float* hU = (const float*)d_in[2];
    const float* hb = (const float*)d_in[3];
    const float* fW = (const float*)d_in[4];
    const float* fb = (const float*)d_in[5];
    const float* iW = (const float*)d_in[6];
    const float* ib = (const float*)d_in[7];
    const float* cW = (const float*)d_in[8];
    const float* cb = (const float*)d_in[9];
    const float* oW = (const float*)d_in[10];
    const float* ob = (const float*)d_in[11];
    const float* tW = (const float*)d_in[12];
    const float* tb = (const float*)d_in[13];
    const float* yW = (const float*)d_in[14];
    const float* yb = (const float*)d_in[15];
    const float* h0 = (const float*)d_in[16];
    float* out = (float*)d_out;

    uint4* wfrag = (uint4*)d_ws;    // 7*8192 uint4 = 896 KB

    hipFuncSetAttribute((const void*)rnn_phase1,
                        hipFuncAttributeMaxDynamicSharedMemorySize, 147456);
    hipFuncSetAttribute((const void*)rnn_phase2,
                        hipFuncAttributeMaxDynamicSharedMemorySize, 81920);

    convert_frag<<<dim3(7 * 8192 / 256), dim3(256), 0, stream>>>(
        hU, fW, iW, cW, oW, tW, yW, wfrag);
    rnn_phase1<<<dim3(kB / 16), dim3(256), 147456, stream>>>(
        z, hW, hb, fb, ib, cb, h0, wfrag, (unsigned*)out);
    rnn_phase2<<<dim3((kB * kS) / 32), dim3(256), 81920, stream>>>(
        ob, tb, yb, wfrag, out);
}

// Round 13
// 2495.300 us; speedup vs baseline: 1.5995x; 1.5995x over previous
//
#include <hip/hip_runtime.h>

constexpr int kB = 256;
constexpr int kS = 512;
constexpr int kU = 256;
constexpr float kL2E = 1.4426950408889634f;   // log2(e)

typedef _Float16 f16x2 __attribute__((ext_vector_type(2)));
typedef _Float16 f16x8 __attribute__((ext_vector_type(8)));
typedef float    f32x4 __attribute__((ext_vector_type(4)));
typedef unsigned u32x4 __attribute__((ext_vector_type(4)));

// activations on PRE-SCALED inputs (x already multiplied by log2e resp.
// 2*log2e via weight/bias prescale): raw v_exp_f32 (=2^x) + v_rcp.
__device__ __forceinline__ float sigm2(float x) {      // x = log2e * y
    return __builtin_amdgcn_rcpf(1.0f + __builtin_amdgcn_exp2f(-x));
}
__device__ __forceinline__ float tanh2(float x) {      // x = 2*log2e * y
    return 1.0f - 2.0f * __builtin_amdgcn_rcpf(__builtin_amdgcn_exp2f(x) + 1.0f);
}
__device__ __forceinline__ unsigned packh2(float lo, float hi) {
    f16x2 h; h.x = (_Float16)lo; h.y = (_Float16)hi;
    return __builtin_bit_cast(unsigned, h);
}
// frag-linear 16x256 fp16 A-tile with XOR bank swizzle (uniform at write/read;
// involution on bits>=4, keeps 16B reads contiguous, kills the 8-way alias —
// verified round 12: conflicts 3.15M -> 1K).
__device__ __forceinline__ int afrag_byte(int m, int k) {
    const int b = (k >> 5) * 1024 + ((m & 15) + 16 * ((k >> 3) & 3)) * 16 + (k & 7) * 2;
    return b ^ (((b >> 8) & 3) << 4);
}
__device__ __forceinline__ int ard(int kt, int lane) {
    const int b = kt * 1024 + lane * 16;
    return b ^ (((b >> 8) & 3) << 4);
}

// ---------------------------------------------------------------------------
// ws layout:
//   [0, 896K)      uint4 B-frag weights, 7 mats, PERMUTED cols, PRE-SCALED:
//                  idx = mat*8192 + (nt*8+kt)*64 + lane
//                  true col n = 32*(nt>>1) + 2*(l&15) + (nt&1)
//                  mats: 0=hU(x2L) 1=fW(xL) 2=iW(xL) 3=cW(x2L) 4=oW(xL)
//                        5=tW(x2L) 6=yW(xL)
//   [896K, ~1.15M) embT: (hW[zt][c] + hb[c]) * 2L, f32, 257x256
// ---------------------------------------------------------------------------
__global__ __launch_bounds__(256) void convert_frag(
    const float* __restrict__ hU, const float* __restrict__ fW,
    const float* __restrict__ iW, const float* __restrict__ cW,
    const float* __restrict__ oW, const float* __restrict__ tW,
    const float* __restrict__ yW, uint4* __restrict__ wfrag)
{
    const int idx = blockIdx.x * 256 + threadIdx.x;   // 7*8192
    const int mat = idx >> 13;
    const int r   = idx & 8191;
    const int lane = r & 63;
    const int kt   = (r >> 6) & 7;
    const int nt   = r >> 9;
    const float* W = mat == 0 ? hU : mat == 1 ? fW : mat == 2 ? iW :
                     mat == 3 ? cW : mat == 4 ? oW : mat == 5 ? tW : yW;
    const float sc = (mat == 0 || mat == 3 || mat == 5) ? 2.0f * kL2E : kL2E;
    const int n  = 32 * (nt >> 1) + 2 * (lane & 15) + (nt & 1);
    const int k0 = kt * 32 + 8 * (lane >> 4);
    uint4 u;
    u.x = packh2(sc * W[(k0 + 0) * kU + n], sc * W[(k0 + 1) * kU + n]);
    u.y = packh2(sc * W[(k0 + 2) * kU + n], sc * W[(k0 + 3) * kU + n]);
    u.z = packh2(sc * W[(k0 + 4) * kU + n], sc * W[(k0 + 5) * kU + n]);
    u.w = packh2(sc * W[(k0 + 6) * kU + n], sc * W[(k0 + 7) * kU + n]);
    wfrag[idx] = u;
}

__global__ __launch_bounds__(256) void convert_emb(
    const float* __restrict__ hW, const float* __restrict__ hb,
    float* __restrict__ embT)
{
    const int idx = blockIdx.x * 256 + threadIdx.x;   // 257*256
    const int c = idx & 255;
    embT[idx] = (hW[idx] + hb[c]) * (2.0f * kL2E);
}

// ---------------------------------------------------------------------------
// Phase 1: sequential recurrence, weight-resident, 2 waves/SIMD (round-11
// structure + round-12 swizzle + exp2 prescale).
// 16 blocks x 512 threads (8 waves). Wave w owns tiles nt0=2w, nt1=2w+1 =
// true cols c0=32w+2*m16, c0+1. hU in LDS (128 KB); fW,iW pinned AGPR (128),
// cW pinned VGPR (64). h/h1 in swizzled frag-linear LDS A-tiles.
// Output: packed u32 (h fp16 lo | h1 fp16 hi), uint2 per lane per row.
// ---------------------------------------------------------------------------

#define MFMA16(A, W, Acc) __builtin_amdgcn_mfma_f32_16x16x32_f16( \
    (A), __builtin_bit_cast(f16x8, (W)), (Acc), 0, 0, 0)

#define LOADW8(pre, moff, nt)                                       \
  u32x4 pre##_0 = wfragv[(moff) + ((nt)*8+0)*64 + lane];            \
  u32x4 pre##_1 = wfragv[(moff) + ((nt)*8+1)*64 + lane];            \
  u32x4 pre##_2 = wfragv[(moff) + ((nt)*8+2)*64 + lane];            \
  u32x4 pre##_3 = wfragv[(moff) + ((nt)*8+3)*64 + lane];            \
  u32x4 pre##_4 = wfragv[(moff) + ((nt)*8+4)*64 + lane];            \
  u32x4 pre##_5 = wfragv[(moff) + ((nt)*8+5)*64 + lane];            \
  u32x4 pre##_6 = wfragv[(moff) + ((nt)*8+6)*64 + lane];            \
  u32x4 pre##_7 = wfragv[(moff) + ((nt)*8+7)*64 + lane];

#define PINA8(pre) asm volatile("" : "+a"(pre##_0), "+a"(pre##_1),  \
  "+a"(pre##_2), "+a"(pre##_3), "+a"(pre##_4), "+a"(pre##_5),       \
  "+a"(pre##_6), "+a"(pre##_7));
#define PINV8(pre) asm volatile("" : "+v"(pre##_0), "+v"(pre##_1),  \
  "+v"(pre##_2), "+v"(pre##_3), "+v"(pre##_4), "+v"(pre##_5),       \
  "+v"(pre##_6), "+v"(pre##_7));

#define GATE_KT(kt) {                                               \
  const f16x8 A = *(const f16x8*)(hAb + ard(kt, lane));             \
  F0 = MFMA16(A, wfA_##kt, F0);                                     \
  I0 = MFMA16(A, wiA_##kt, I0);                                     \
  C0 = MFMA16(A, wcA_##kt, C0);                                     \
  F1 = MFMA16(A, wfB_##kt, F1);                                     \
  I1 = MFMA16(A, wiB_##kt, I1);                                     \
  C1 = MFMA16(A, wcB_##kt, C1); }

__global__ __launch_bounds__(512, 2) void rnn_phase1(
    const int* __restrict__ z,
    const float* __restrict__ embT,
    const float* __restrict__ fb, const float* __restrict__ ib,
    const float* __restrict__ cb,
    const float* __restrict__ h0,
    const uint4* __restrict__ wfrag,
    unsigned* __restrict__ outu)
{
    extern __shared__ __align__(16) char smem[];
    uint4* hUl  = (uint4*)smem;                // 131072 B
    char*  h1Ab = smem + 131072;               // 8192 B
    char*  hAb  = smem + 139264;               // 8192 B

    const int tid  = threadIdx.x;
    const int w    = tid >> 6;                 // 0..7
    const int lane = tid & 63;
    const int m16  = lane & 15;
    const int g    = lane >> 4;
    const int b0   = blockIdx.x * 16;
    const int nt0  = 2 * w, nt1 = nt0 + 1;
    const int c0   = 32 * w + 2 * m16;         // true col (even); c1 = c0+1

    const u32x4* wfragv = (const u32x4*)wfrag;

    for (int i = tid; i < 8192; i += 512) hUl[i] = wfrag[i];

    LOADW8(wfA,  8192, nt0) LOADW8(wfB,  8192, nt1)
    LOADW8(wiA, 16384, nt0) LOADW8(wiB, 16384, nt1)
    LOADW8(wcA, 24576, nt0) LOADW8(wcB, 24576, nt1)
    PINA8(wfA) PINA8(wfB) PINA8(wiA) PINA8(wiB)
    PINV8(wcA) PINV8(wcB)

    // biases pre-scaled once (f,i: xL for sigm; c: x2L for tanh)
    float2 fb2 = *(const float2*)&fb[c0];
    float2 ib2 = *(const float2*)&ib[c0];
    float2 cb2 = *(const float2*)&cb[c0];
    fb2.x *= kL2E;        fb2.y *= kL2E;
    ib2.x *= kL2E;        ib2.y *= kL2E;
    cb2.x *= 2.0f * kL2E; cb2.y *= 2.0f * kL2E;

    float h1m0[4], h1m1[4];
    {
        const float2 h02 = *(const float2*)&h0[c0];
        #pragma unroll
        for (int r = 0; r < 4; ++r) { h1m0[r] = h02.x; h1m1[r] = h02.y; }
    }
    // init h1A tile (paired b32 writes, swizzled)
    for (int i = tid; i < 2048; i += 512) {
        const int m = i >> 7, kp = i & 127;
        *(unsigned*)(h1Ab + afrag_byte(m, 2 * kp)) =
            packh2(h0[2 * kp], h0[2 * kp + 1]);
    }
    __syncthreads();

    const unsigned obase0 = (unsigned)((b0 + 4 * g) * kS) * kU + c0;

    for (int t = 0; t < kS; ++t) {
        // embedding gathers: embT already has +hb and x2L folded in
        float2 e2[4];
        #pragma unroll
        for (int r = 0; r < 4; ++r) {
            int zt = 0;
            if (t > 0) zt = z[(b0 + 4 * g + r) * kS + t - 1] + 1;
            e2[r] = *(const float2*)&embT[(size_t)zt * kU + c0];
        }

        // a = h1 @ hU (hU pre-scaled x2L)
        f32x4 a0 = {0.f, 0.f, 0.f, 0.f}, a1 = {0.f, 0.f, 0.f, 0.f};
        #pragma unroll
        for (int kt = 0; kt < 8; ++kt) {
            const f16x8 A = *(const f16x8*)(h1Ab + ard(kt, lane));
            const f16x8 B0 = __builtin_bit_cast(f16x8, hUl[(nt0 * 8 + kt) * 64 + lane]);
            const f16x8 B1 = __builtin_bit_cast(f16x8, hUl[(nt1 * 8 + kt) * 64 + lane]);
            a0 = __builtin_amdgcn_mfma_f32_16x16x32_f16(A, B0, a0, 0, 0, 0);
            a1 = __builtin_amdgcn_mfma_f32_16x16x32_f16(A, B1, a1, 0, 0, 0);
        }

        // h = tanh2(a + e) -> hA (one b32 per row pair, swizzled)
        float hv0[4], hv1[4];
        #pragma unroll
        for (int r = 0; r < 4; ++r) {
            hv0[r] = tanh2(a0[r] + e2[r].x);
            hv1[r] = tanh2(a1[r] + e2[r].y);
            *(unsigned*)(hAb + afrag_byte(4 * g + r, c0)) = packh2(hv0[r], hv1[r]);
        }
        __syncthreads();   // barrier 1: hA complete; h1A reads done

        // fused gate pass: F, I, C (register-resident B, pre-scaled)
        f32x4 F0 = {0.f,0.f,0.f,0.f}, F1 = {0.f,0.f,0.f,0.f};
        f32x4 I0 = {0.f,0.f,0.f,0.f}, I1 = {0.f,0.f,0.f,0.f};
        f32x4 C0 = {0.f,0.f,0.f,0.f}, C1 = {0.f,0.f,0.f,0.f};
        GATE_KT(0) GATE_KT(1) GATE_KT(2) GATE_KT(3)
        GATE_KT(4) GATE_KT(5) GATE_KT(6) GATE_KT(7)

        // update h1, pack (h,h1) uint2 store, refresh h1A (b32, swizzled)
        const unsigned tOff = (unsigned)t * kU;
        #pragma unroll
        for (int r = 0; r < 4; ++r) {
            const float ff0 = sigm2(F0[r] + fb2.x);
            const float ii0 = sigm2(I0[r] + ib2.x);
            const float cc0 = tanh2(C0[r] + cb2.x);
            const float ff1 = sigm2(F1[r] + fb2.y);
            const float ii1 = sigm2(I1[r] + ib2.y);
            const float cc1 = tanh2(C1[r] + cb2.y);
            h1m0[r] = h1m0[r] * ff0 + cc0 * ii0;
            h1m1[r] = h1m1[r] * ff1 + cc1 * ii1;
            uint2 ov;
            ov.x = packh2(hv0[r], h1m0[r]);
            ov.y = packh2(hv1[r], h1m1[r]);
            *(uint2*)&outu[obase0 + ((unsigned)r << 17) + tOff] = ov;
            *(unsigned*)(h1Ab + afrag_byte(4 * g + r, c0)) =
                packh2(h1m0[r], h1m1[r]);
        }
        __syncthreads();   // barrier 2: h1A refreshed
    }
}

// ---------------------------------------------------------------------------
// Phase 2: output head, MFMA. 4096 blocks x 256 threads (4 waves), 32 rows.
// o = sigm2(h@oW'+ob*L), g = o*h1, tt = tanh2(g@tW'+tb*2L),
// y = softmax2(tt@yW'+yb*L). All weights pre-scaled; swizzled A-tiles.
// ---------------------------------------------------------------------------
#define P2_MATVEC(MOFF)                                                   \
  {                                                                       \
    f16x8 Af[2][8];                                                       \
    _Pragma("unroll") for (int kt = 0; kt < 8; ++kt) {                    \
      Af[0][kt] = *(const f16x8*)(aT + ard(kt, lane));                    \
      Af[1][kt] = *(const f16x8*)(aT + 8192 + ard(kt, lane));             \
    }                                                                     \
    _Pragma("unroll") for (int ntl = 0; ntl < 4; ++ntl) {                 \
      const int nt = 4 * w + ntl;                                         \
      acc[0][ntl] = (f32x4){0.f, 0.f, 0.f, 0.f};                          \
      acc[1][ntl] = (f32x4){0.f, 0.f, 0.f, 0.f};                          \
      _Pragma("unroll") for (int kt = 0; kt < 8; ++kt) {                  \
        const f16x8 Bf = __builtin_bit_cast(f16x8,                        \
            wfrag[(MOFF) + (nt * 8 + kt) * 64 + lane]);                   \
        acc[0][ntl] = __builtin_amdgcn_mfma_f32_16x16x32_f16(             \
            Af[0][kt], Bf, acc[0][ntl], 0, 0, 0);                         \
        acc[1][ntl] = __builtin_amdgcn_mfma_f32_16x16x32_f16(             \
            Af[1][kt], Bf, acc[1][ntl], 0, 0, 0);                         \
      }                                                                   \
    }                                                                     \
  }

__global__ __launch_bounds__(256, 2) void rnn_phase2(
    const float* __restrict__ ob_, const float* __restrict__ tb,
    const float* __restrict__ yb,
    const uint4* __restrict__ wfrag,
    float* __restrict__ out)
{
    extern __shared__ __align__(16) char smem[];
    unsigned* pkl = (unsigned*)smem;           // 32*256 u32 = 32768 B
    char*     aT  = smem + 32768;              // 2 A-tiles = 16384 B
    float*    lg  = (float*)(smem + 49152);    // logits 32768 B

    const int tid  = threadIdx.x;
    const int w    = tid >> 6;
    const int lane = tid & 63;
    const int m16  = lane & 15;
    const int g    = lane >> 4;
    const size_t rowbase = (size_t)blockIdx.x * 32;
    unsigned* outu = (unsigned*)out;

    {
        const uint4* src = (const uint4*)(outu + rowbase * kU);
        uint4* dst = (uint4*)pkl;
        #pragma unroll
        for (int i = 0; i < 8; ++i) dst[i * 256 + tid] = src[i * 256 + tid];
    }
    __syncthreads();

    // build h A-tiles (lo halves, paired b32, swizzled)
    for (int i = tid; i < 4096; i += 256) {
        const int row = i >> 7, kp = i & 127;
        const unsigned p0 = pkl[row * 256 + 2 * kp];
        const unsigned p1 = pkl[row * 256 + 2 * kp + 1];
        *(unsigned*)(aT + (row >> 4) * 8192 + afrag_byte(row & 15, 2 * kp)) =
            (p0 & 0xFFFFu) | (p1 << 16);
    }
    __syncthreads();

    const int cA = 64 * w + 2 * m16;
    const int cB = cA + 32;

    f32x4 acc[2][4];

    // ---- o = sigm2(h @ oW' + ob*L); g = o * h1 -> gA tiles ----
    P2_MATVEC(4 * 8192)
    __syncthreads();
    {
        float2 obA = *(const float2*)&ob_[cA];
        float2 obB = *(const float2*)&ob_[cB];
        obA.x *= kL2E; obA.y *= kL2E; obB.x *= kL2E; obB.y *= kL2E;
        #pragma unroll
        for (int mt = 0; mt < 2; ++mt) {
            #pragma unroll
            for (int r = 0; r < 4; ++r) {
                const int row = mt * 16 + 4 * g + r;
                const f16x2 qA0 = __builtin_bit_cast(f16x2, pkl[row * 256 + cA]);
                const f16x2 qA1 = __builtin_bit_cast(f16x2, pkl[row * 256 + cA + 1]);
                const f16x2 qB0 = __builtin_bit_cast(f16x2, pkl[row * 256 + cB]);
                const f16x2 qB1 = __builtin_bit_cast(f16x2, pkl[row * 256 + cB + 1]);
                const float g0 = sigm2(acc[mt][0][r] + obA.x) * (float)qA0.y;
                const float g1 = sigm2(acc[mt][1][r] + obA.y) * (float)qA1.y;
                const float g2 = sigm2(acc[mt][2][r] + obB.x) * (float)qB0.y;
                const float g3 = sigm2(acc[mt][3][r] + obB.y) * (float)qB1.y;
                char* tile = aT + mt * 8192;
                *(unsigned*)(tile + afrag_byte(row & 15, cA)) = packh2(g0, g1);
                *(unsigned*)(tile + afrag_byte(row & 15, cB)) = packh2(g2, g3);
            }
        }
    }
    __syncthreads();

    // ---- tt = tanh2(g @ tW' + tb*2L) -> ttA tiles ----
    P2_MATVEC(5 * 8192)
    __syncthreads();
    {
        float2 tbA = *(const float2*)&tb[cA];
        float2 tbB = *(const float2*)&tb[cB];
        tbA.x *= 2.0f * kL2E; tbA.y *= 2.0f * kL2E;
        tbB.x *= 2.0f * kL2E; tbB.y *= 2.0f * kL2E;
        #pragma unroll
        for (int mt = 0; mt < 2; ++mt) {
            #pragma unroll
            for (int r = 0; r < 4; ++r) {
                const int row = mt * 16 + 4 * g + r;
                const float t0 = tanh2(acc[mt][0][r] + tbA.x);
                const float t1 = tanh2(acc[mt][1][r] + tbA.y);
                const float t2 = tanh2(acc[mt][2][r] + tbB.x);
                const float t3 = tanh2(acc[mt][3][r] + tbB.y);
                char* tile = aT + mt * 8192;
                *(unsigned*)(tile + afrag_byte(row & 15, cA)) = packh2(t0, t1);
                *(unsigned*)(tile + afrag_byte(row & 15, cB)) = packh2(t2, t3);
            }
        }
    }
    __syncthreads();

    // ---- logits (xL) = tt @ yW' + yb*L ----
    P2_MATVEC(6 * 8192)
    {
        float2 ybA = *(const float2*)&yb[cA];
        float2 ybB = *(const float2*)&yb[cB];
        ybA.x *= kL2E; ybA.y *= kL2E; ybB.x *= kL2E; ybB.y *= kL2E;
        #pragma unroll
        for (int mt = 0; mt < 2; ++mt) {
            #pragma unroll
            for (int r = 0; r < 4; ++r) {
                const int row = mt * 16 + 4 * g + r;
                float2 lA, lB;
                lA.x = acc[mt][0][r] + ybA.x;  lA.y = acc[mt][1][r] + ybA.y;
                lB.x = acc[mt][2][r] + ybB.x;  lB.y = acc[mt][3][r] + ybB.y;
                *(float2*)&lg[row * 256 + cA] = lA;
                *(float2*)&lg[row * 256 + cB] = lB;
            }
        }
    }
    __syncthreads();

    // softmax in log2 domain: logits are xL, so 2^(l - m) = e^(orig - m')
    for (int q = 0; q < 8; ++q) {
        const int r = w * 8 + q;
        const float4 v = *(const float4*)&lg[r * 256 + lane * 4];
        float m = fmaxf(fmaxf(v.x, v.y), fmaxf(v.z, v.w));
        #pragma unroll
        for (int off = 32; off > 0; off >>= 1) m = fmaxf(m, __shfl_xor(m, off, 64));
        const float e0 = __builtin_amdgcn_exp2f(v.x - m);
        const float e1 = __builtin_amdgcn_exp2f(v.y - m);
        const float e2 = __builtin_amdgcn_exp2f(v.z - m);
        const float e3 = __builtin_amdgcn_exp2f(v.w - m);
        float s = e0 + e1 + e2 + e3;
        #pragma unroll
        for (int off = 32; off > 0; off >>= 1) s += __shfl_xor(s, off, 64);
        const float inv = 1.0f / s;
        float4 o4; o4.x = e0 * inv; o4.y = e1 * inv; o4.z = e2 * inv; o4.w = e3 * inv;
        *(float4*)&out[(rowbase + r) * kU + lane * 4] = o4;
    }
}

extern "C" void kernel_launch(void* const* d_in, const int* in_sizes, int n_in,
                              void* d_out, int out_size, void* d_ws, size_t ws_size,
                              hipStream_t stream) {
    const int*   z  = (const int*)d_in[0];
    const float* hW = (const float*)d_in[1];
    const float* hU = (const float*)d_in[2];
    const float* hb = (const float*)d_in[3];
    const float* fW = (const float*)d_in[4];
    const float* fb = (const float*)d_in[5];
    const float* iW = (const float*)d_in[6];
    const float* ib = (const float*)d_in[7];
    const float* cW = (const float*)d_in[8];
    const float* cb = (const float*)d_in[9];
    const float* oW = (const float*)d_in[10];
    const float* ob = (const float*)d_in[11];
    const float* tW = (const float*)d_in[12];
    const float* tb = (const float*)d_in[13];
    const float* yW = (const float*)d_in[14];
    const float* yb = (const float*)d_in[15];
    const float* h0 = (const float*)d_in[16];
    float* out = (float*)d_out;

    uint4* wfrag = (uint4*)d_ws;                         // 7*8192 uint4 = 896 KB
    float* embT  = (float*)((char*)d_ws + 7 * 8192 * 16); // 257*256 f32 = 257 KB

    hipFuncSetAttribute((const void*)rnn_phase1,
                        hipFuncAttributeMaxDynamicSharedMemorySize, 147456);
    hipFuncSetAttribute((const void*)rnn_phase2,
                        hipFuncAttributeMaxDynamicSharedMemorySize, 81920);

    convert_frag<<<dim3(7 * 8192 / 256), dim3(256), 0, stream>>>(
        hU, fW, iW, cW, oW, tW, yW, wfrag);
    convert_emb<<<dim3(257), dim3(256), 0, stream>>>(hW, hb, embT);
    rnn_phase1<<<dim3(kB / 16), dim3(512), 147456, stream>>>(
        z, embT, fb, ib, cb, h0, wfrag, (unsigned*)out);
    rnn_phase2<<<dim3((kB * kS) / 32), dim3(256), 81920, stream>>>(
        ob, tb, yb, wfrag, out);
}

// Round 14
// 1946.267 us; speedup vs baseline: 2.0507x; 1.2821x over previous
//
#include <hip/hip_runtime.h>

constexpr int kB = 256;
constexpr int kS = 512;
constexpr int kU = 256;
constexpr float kL2E = 1.4426950408889634f;   // log2(e)

typedef _Float16 f16x2 __attribute__((ext_vector_type(2)));
typedef _Float16 f16x8 __attribute__((ext_vector_type(8)));
typedef float    f32x4 __attribute__((ext_vector_type(4)));
typedef unsigned u32x4 __attribute__((ext_vector_type(4)));

// activations on PRE-SCALED inputs (x already multiplied by log2e resp.
// 2*log2e via weight/bias prescale): raw v_exp_f32 (=2^x) + v_rcp.
__device__ __forceinline__ float sigm2(float x) {      // x = log2e * y
    return __builtin_amdgcn_rcpf(1.0f + __builtin_amdgcn_exp2f(-x));
}
__device__ __forceinline__ float tanh2(float x) {      // x = 2*log2e * y
    return 1.0f - 2.0f * __builtin_amdgcn_rcpf(__builtin_amdgcn_exp2f(x) + 1.0f);
}
__device__ __forceinline__ unsigned packh2(float lo, float hi) {
    f16x2 h; h.x = (_Float16)lo; h.y = (_Float16)hi;
    return __builtin_bit_cast(unsigned, h);
}
// frag-linear 16x256 fp16 A-tile, UNSWIZZLED (round-13 lesson: the XOR swizzle
// broke offset-immediate addressing and cost 28% in stalls; the 8-way write
// conflict it fixed is only ~4.5%/step — keep the simple layout).
__device__ __forceinline__ int afrag_byte(int m, int k) {
    return (k >> 5) * 1024 + ((m & 15) + 16 * ((k >> 3) & 3)) * 16 + (k & 7) * 2;
}

// ---------------------------------------------------------------------------
// ws layout:
//   [0, 896K)      uint4 B-frag weights, 7 mats, PERMUTED cols, PRE-SCALED:
//                  idx = mat*8192 + (nt*8+kt)*64 + lane
//                  true col n = 32*(nt>>1) + 2*(l&15) + (nt&1)
//                  mats: 0=hU(x2L) 1=fW(xL) 2=iW(xL) 3=cW(x2L) 4=oW(xL)
//                        5=tW(x2L) 6=yW(xL)
//   [896K, ~1.15M) embT: (hW[zt][c] + hb[c]) * 2L, f32, 257x256
// ---------------------------------------------------------------------------
__global__ __launch_bounds__(256) void convert_frag(
    const float* __restrict__ hU, const float* __restrict__ fW,
    const float* __restrict__ iW, const float* __restrict__ cW,
    const float* __restrict__ oW, const float* __restrict__ tW,
    const float* __restrict__ yW, uint4* __restrict__ wfrag)
{
    const int idx = blockIdx.x * 256 + threadIdx.x;   // 7*8192
    const int mat = idx >> 13;
    const int r   = idx & 8191;
    const int lane = r & 63;
    const int kt   = (r >> 6) & 7;
    const int nt   = r >> 9;
    const float* W = mat == 0 ? hU : mat == 1 ? fW : mat == 2 ? iW :
                     mat == 3 ? cW : mat == 4 ? oW : mat == 5 ? tW : yW;
    const float sc = (mat == 0 || mat == 3 || mat == 5) ? 2.0f * kL2E : kL2E;
    const int n  = 32 * (nt >> 1) + 2 * (lane & 15) + (nt & 1);
    const int k0 = kt * 32 + 8 * (lane >> 4);
    uint4 u;
    u.x = packh2(sc * W[(k0 + 0) * kU + n], sc * W[(k0 + 1) * kU + n]);
    u.y = packh2(sc * W[(k0 + 2) * kU + n], sc * W[(k0 + 3) * kU + n]);
    u.z = packh2(sc * W[(k0 + 4) * kU + n], sc * W[(k0 + 5) * kU + n]);
    u.w = packh2(sc * W[(k0 + 6) * kU + n], sc * W[(k0 + 7) * kU + n]);
    wfrag[idx] = u;
}

__global__ __launch_bounds__(256) void convert_emb(
    const float* __restrict__ hW, const float* __restrict__ hb,
    float* __restrict__ embT)
{
    const int idx = blockIdx.x * 256 + threadIdx.x;   // 257*256
    const int c = idx & 255;
    embT[idx] = (hW[idx] + hb[c]) * (2.0f * kL2E);
}

// ---------------------------------------------------------------------------
// Phase 1: sequential recurrence, weight-resident, 2 waves/SIMD
// (exact round-11 structure + exp2 prescale; swizzle reverted).
// 16 blocks x 512 threads (8 waves). Wave w owns tiles nt0=2w, nt1=2w+1 =
// true cols c0=32w+2*m16, c0+1. hU in LDS (128 KB); fW,iW pinned AGPR (128),
// cW pinned VGPR (64). h/h1 in frag-linear LDS A-tiles; 2 barriers/step.
// Output: packed u32 (h fp16 lo | h1 fp16 hi), uint2 per lane per row.
// ---------------------------------------------------------------------------

#define MFMA16(A, W, Acc) __builtin_amdgcn_mfma_f32_16x16x32_f16( \
    (A), __builtin_bit_cast(f16x8, (W)), (Acc), 0, 0, 0)

#define LOADW8(pre, moff, nt)                                       \
  u32x4 pre##_0 = wfragv[(moff) + ((nt)*8+0)*64 + lane];            \
  u32x4 pre##_1 = wfragv[(moff) + ((nt)*8+1)*64 + lane];            \
  u32x4 pre##_2 = wfragv[(moff) + ((nt)*8+2)*64 + lane];            \
  u32x4 pre##_3 = wfragv[(moff) + ((nt)*8+3)*64 + lane];            \
  u32x4 pre##_4 = wfragv[(moff) + ((nt)*8+4)*64 + lane];            \
  u32x4 pre##_5 = wfragv[(moff) + ((nt)*8+5)*64 + lane];            \
  u32x4 pre##_6 = wfragv[(moff) + ((nt)*8+6)*64 + lane];            \
  u32x4 pre##_7 = wfragv[(moff) + ((nt)*8+7)*64 + lane];

#define PINA8(pre) asm volatile("" : "+a"(pre##_0), "+a"(pre##_1),  \
  "+a"(pre##_2), "+a"(pre##_3), "+a"(pre##_4), "+a"(pre##_5),       \
  "+a"(pre##_6), "+a"(pre##_7));
#define PINV8(pre) asm volatile("" : "+v"(pre##_0), "+v"(pre##_1),  \
  "+v"(pre##_2), "+v"(pre##_3), "+v"(pre##_4), "+v"(pre##_5),       \
  "+v"(pre##_6), "+v"(pre##_7));

#define GATE_KT(kt) {                                               \
  const f16x8 A = *(const f16x8*)(hAb + (kt) * 1024 + lane * 16);   \
  F0 = MFMA16(A, wfA_##kt, F0);                                     \
  I0 = MFMA16(A, wiA_##kt, I0);                                     \
  C0 = MFMA16(A, wcA_##kt, C0);                                     \
  F1 = MFMA16(A, wfB_##kt, F1);                                     \
  I1 = MFMA16(A, wiB_##kt, I1);                                     \
  C1 = MFMA16(A, wcB_##kt, C1); }

__global__ __launch_bounds__(512, 2) void rnn_phase1(
    const int* __restrict__ z,
    const float* __restrict__ embT,
    const float* __restrict__ fb, const float* __restrict__ ib,
    const float* __restrict__ cb,
    const float* __restrict__ h0,
    const uint4* __restrict__ wfrag,
    unsigned* __restrict__ outu)
{
    extern __shared__ __align__(16) char smem[];
    uint4* hUl  = (uint4*)smem;                // 131072 B
    char*  h1Ab = smem + 131072;               // 8192 B
    char*  hAb  = smem + 139264;               // 8192 B

    const int tid  = threadIdx.x;
    const int w    = tid >> 6;                 // 0..7
    const int lane = tid & 63;
    const int m16  = lane & 15;
    const int g    = lane >> 4;
    const int b0   = blockIdx.x * 16;
    const int nt0  = 2 * w, nt1 = nt0 + 1;
    const int c0   = 32 * w + 2 * m16;         // true col (even); c1 = c0+1

    const u32x4* wfragv = (const u32x4*)wfrag;

    for (int i = tid; i < 8192; i += 512) hUl[i] = wfrag[i];

    LOADW8(wfA,  8192, nt0) LOADW8(wfB,  8192, nt1)
    LOADW8(wiA, 16384, nt0) LOADW8(wiB, 16384, nt1)
    LOADW8(wcA, 24576, nt0) LOADW8(wcB, 24576, nt1)
    PINA8(wfA) PINA8(wfB) PINA8(wiA) PINA8(wiB)
    PINV8(wcA) PINV8(wcB)

    // biases pre-scaled once (f,i: xL for sigm; c: x2L for tanh)
    float2 fb2 = *(const float2*)&fb[c0];
    float2 ib2 = *(const float2*)&ib[c0];
    float2 cb2 = *(const float2*)&cb[c0];
    fb2.x *= kL2E;        fb2.y *= kL2E;
    ib2.x *= kL2E;        ib2.y *= kL2E;
    cb2.x *= 2.0f * kL2E; cb2.y *= 2.0f * kL2E;

    float h1m0[4], h1m1[4];
    {
        const float2 h02 = *(const float2*)&h0[c0];
        #pragma unroll
        for (int r = 0; r < 4; ++r) { h1m0[r] = h02.x; h1m1[r] = h02.y; }
    }
    // init h1A tile (paired b32 writes)
    for (int i = tid; i < 2048; i += 512) {
        const int m = i >> 7, kp = i & 127;
        *(unsigned*)(h1Ab + afrag_byte(m, 2 * kp)) =
            packh2(h0[2 * kp], h0[2 * kp + 1]);
    }
    __syncthreads();

    const unsigned obase0 = (unsigned)((b0 + 4 * g) * kS) * kU + c0;

    for (int t = 0; t < kS; ++t) {
        // embedding gathers: embT already has +hb and x2L folded in
        float2 e2[4];
        #pragma unroll
        for (int r = 0; r < 4; ++r) {
            int zt = 0;
            if (t > 0) zt = z[(b0 + 4 * g + r) * kS + t - 1] + 1;
            e2[r] = *(const float2*)&embT[(size_t)zt * kU + c0];
        }

        // a = h1 @ hU (hU pre-scaled x2L)
        f32x4 a0 = {0.f, 0.f, 0.f, 0.f}, a1 = {0.f, 0.f, 0.f, 0.f};
        #pragma unroll
        for (int kt = 0; kt < 8; ++kt) {
            const f16x8 A = *(const f16x8*)(h1Ab + kt * 1024 + lane * 16);
            const f16x8 B0 = __builtin_bit_cast(f16x8, hUl[(nt0 * 8 + kt) * 64 + lane]);
            const f16x8 B1 = __builtin_bit_cast(f16x8, hUl[(nt1 * 8 + kt) * 64 + lane]);
            a0 = __builtin_amdgcn_mfma_f32_16x16x32_f16(A, B0, a0, 0, 0, 0);
            a1 = __builtin_amdgcn_mfma_f32_16x16x32_f16(A, B1, a1, 0, 0, 0);
        }

        // h = tanh2(a + e) -> hA (one b32 per row pair)
        float hv0[4], hv1[4];
        #pragma unroll
        for (int r = 0; r < 4; ++r) {
            hv0[r] = tanh2(a0[r] + e2[r].x);
            hv1[r] = tanh2(a1[r] + e2[r].y);
            *(unsigned*)(hAb + afrag_byte(4 * g + r, c0)) = packh2(hv0[r], hv1[r]);
        }
        __syncthreads();   // barrier 1: hA complete; h1A reads done

        // fused gate pass: F, I, C (register-resident B, pre-scaled)
        f32x4 F0 = {0.f,0.f,0.f,0.f}, F1 = {0.f,0.f,0.f,0.f};
        f32x4 I0 = {0.f,0.f,0.f,0.f}, I1 = {0.f,0.f,0.f,0.f};
        f32x4 C0 = {0.f,0.f,0.f,0.f}, C1 = {0.f,0.f,0.f,0.f};
        GATE_KT(0) GATE_KT(1) GATE_KT(2) GATE_KT(3)
        GATE_KT(4) GATE_KT(5) GATE_KT(6) GATE_KT(7)

        // update h1, pack (h,h1) uint2 store, refresh h1A (b32)
        const unsigned tOff = (unsigned)t * kU;
        #pragma unroll
        for (int r = 0; r < 4; ++r) {
            const float ff0 = sigm2(F0[r] + fb2.x);
            const float ii0 = sigm2(I0[r] + ib2.x);
            const float cc0 = tanh2(C0[r] + cb2.x);
            const float ff1 = sigm2(F1[r] + fb2.y);
            const float ii1 = sigm2(I1[r] + ib2.y);
            const float cc1 = tanh2(C1[r] + cb2.y);
            h1m0[r] = h1m0[r] * ff0 + cc0 * ii0;
            h1m1[r] = h1m1[r] * ff1 + cc1 * ii1;
            uint2 ov;
            ov.x = packh2(hv0[r], h1m0[r]);
            ov.y = packh2(hv1[r], h1m1[r]);
            *(uint2*)&outu[obase0 + ((unsigned)r << 17) + tOff] = ov;
            *(unsigned*)(h1Ab + afrag_byte(4 * g + r, c0)) =
                packh2(h1m0[r], h1m1[r]);
        }
        __syncthreads();   // barrier 2: h1A refreshed
    }
}

// ---------------------------------------------------------------------------
// Phase 2: output head, MFMA. 4096 blocks x 256 threads (4 waves), 32 rows.
// o = sigm2(h@oW'+ob*L), g = o*h1, tt = tanh2(g@tW'+tb*2L),
// y = softmax2(tt@yW'+yb*L). Unswizzled A-tiles (round-11 addressing).
// ---------------------------------------------------------------------------
#define P2_MATVEC(MOFF)                                                   \
  {                                                                       \
    f16x8 Af[2][8];                                                       \
    _Pragma("unroll") for (int kt = 0; kt < 8; ++kt) {                    \
      Af[0][kt] = *(const f16x8*)(aT + kt * 1024 + lane * 16);            \
      Af[1][kt] = *(const f16x8*)(aT + 8192 + kt * 1024 + lane * 16);     \
    }                                                                     \
    _Pragma("unroll") for (int ntl = 0; ntl < 4; ++ntl) {                 \
      const int nt = 4 * w + ntl;                                         \
      acc[0][ntl] = (f32x4){0.f, 0.f, 0.f, 0.f};                          \
      acc[1][ntl] = (f32x4){0.f, 0.f, 0.f, 0.f};                          \
      _Pragma("unroll") for (int kt = 0; kt < 8; ++kt) {                  \
        const f16x8 Bf = __builtin_bit_cast(f16x8,                        \
            wfrag[(MOFF) + (nt * 8 + kt) * 64 + lane]);                   \
        acc[0][ntl] = __builtin_amdgcn_mfma_f32_16x16x32_f16(             \
            Af[0][kt], Bf, acc[0][ntl], 0, 0, 0);                         \
        acc[1][ntl] = __builtin_amdgcn_mfma_f32_16x16x32_f16(             \
            Af[1][kt], Bf, acc[1][ntl], 0, 0, 0);                         \
      }                                                                   \
    }                                                                     \
  }

__global__ __launch_bounds__(256, 2) void rnn_phase2(
    const float* __restrict__ ob_, const float* __restrict__ tb,
    const float* __restrict__ yb,
    const uint4* __restrict__ wfrag,
    float* __restrict__ out)
{
    extern __shared__ __align__(16) char smem[];
    unsigned* pkl = (unsigned*)smem;           // 32*256 u32 = 32768 B
    char*     aT  = smem + 32768;              // 2 A-tiles = 16384 B
    float*    lg  = (float*)(smem + 49152);    // logits 32768 B

    const int tid  = threadIdx.x;
    const int w    = tid >> 6;
    const int lane = tid & 63;
    const int m16  = lane & 15;
    const int g    = lane >> 4;
    const size_t rowbase = (size_t)blockIdx.x * 32;
    unsigned* outu = (unsigned*)out;

    {
        const uint4* src = (const uint4*)(outu + rowbase * kU);
        uint4* dst = (uint4*)pkl;
        #pragma unroll
        for (int i = 0; i < 8; ++i) dst[i * 256 + tid] = src[i * 256 + tid];
    }
    __syncthreads();

    // build h A-tiles (lo halves, paired b32)
    for (int i = tid; i < 4096; i += 256) {
        const int row = i >> 7, kp = i & 127;
        const unsigned p0 = pkl[row * 256 + 2 * kp];
        const unsigned p1 = pkl[row * 256 + 2 * kp + 1];
        *(unsigned*)(aT + (row >> 4) * 8192 + afrag_byte(row & 15, 2 * kp)) =
            (p0 & 0xFFFFu) | (p1 << 16);
    }
    __syncthreads();

    const int cA = 64 * w + 2 * m16;
    const int cB = cA + 32;

    f32x4 acc[2][4];

    // ---- o = sigm2(h @ oW' + ob*L); g = o * h1 -> gA tiles ----
    P2_MATVEC(4 * 8192)
    __syncthreads();
    {
        float2 obA = *(const float2*)&ob_[cA];
        float2 obB = *(const float2*)&ob_[cB];
        obA.x *= kL2E; obA.y *= kL2E; obB.x *= kL2E; obB.y *= kL2E;
        #pragma unroll
        for (int mt = 0; mt < 2; ++mt) {
            #pragma unroll
            for (int r = 0; r < 4; ++r) {
                const int row = mt * 16 + 4 * g + r;
                const f16x2 qA0 = __builtin_bit_cast(f16x2, pkl[row * 256 + cA]);
                const f16x2 qA1 = __builtin_bit_cast(f16x2, pkl[row * 256 + cA + 1]);
                const f16x2 qB0 = __builtin_bit_cast(f16x2, pkl[row * 256 + cB]);
                const f16x2 qB1 = __builtin_bit_cast(f16x2, pkl[row * 256 + cB + 1]);
                const float g0 = sigm2(acc[mt][0][r] + obA.x) * (float)qA0.y;
                const float g1 = sigm2(acc[mt][1][r] + obA.y) * (float)qA1.y;
                const float g2 = sigm2(acc[mt][2][r] + obB.x) * (float)qB0.y;
                const float g3 = sigm2(acc[mt][3][r] + obB.y) * (float)qB1.y;
                char* tile = aT + mt * 8192;
                *(unsigned*)(tile + afrag_byte(row & 15, cA)) = packh2(g0, g1);
                *(unsigned*)(tile + afrag_byte(row & 15, cB)) = packh2(g2, g3);
            }
        }
    }
    __syncthreads();

    // ---- tt = tanh2(g @ tW' + tb*2L) -> ttA tiles ----
    P2_MATVEC(5 * 8192)
    __syncthreads();
    {
        float2 tbA = *(const float2*)&tb[cA];
        float2 tbB = *(const float2*)&tb[cB];
        tbA.x *= 2.0f * kL2E; tbA.y *= 2.0f * kL2E;
        tbB.x *= 2.0f * kL2E; tbB.y *= 2.0f * kL2E;
        #pragma unroll
        for (int mt = 0; mt < 2; ++mt) {
            #pragma unroll
            for (int r = 0; r < 4; ++r) {
                const int row = mt * 16 + 4 * g + r;
                const float t0 = tanh2(acc[mt][0][r] + tbA.x);
                const float t1 = tanh2(acc[mt][1][r] + tbA.y);
                const float t2 = tanh2(acc[mt][2][r] + tbB.x);
                const float t3 = tanh2(acc[mt][3][r] + tbB.y);
                char* tile = aT + mt * 8192;
                *(unsigned*)(tile + afrag_byte(row & 15, cA)) = packh2(t0, t1);
                *(unsigned*)(tile + afrag_byte(row & 15, cB)) = packh2(t2, t3);
            }
        }
    }
    __syncthreads();

    // ---- logits (xL) = tt @ yW' + yb*L ----
    P2_MATVEC(6 * 8192)
    {
        float2 ybA = *(const float2*)&yb[cA];
        float2 ybB = *(const float2*)&yb[cB];
        ybA.x *= kL2E; ybA.y *= kL2E; ybB.x *= kL2E; ybB.y *= kL2E;
        #pragma unroll
        for (int mt = 0; mt < 2; ++mt) {
            #pragma unroll
            for (int r = 0; r < 4; ++r) {
                const int row = mt * 16 + 4 * g + r;
                float2 lA, lB;
                lA.x = acc[mt][0][r] + ybA.x;  lA.y = acc[mt][1][r] + ybA.y;
                lB.x = acc[mt][2][r] + ybB.x;  lB.y = acc[mt][3][r] + ybB.y;
                *(float2*)&lg[row * 256 + cA] = lA;
                *(float2*)&lg[row * 256 + cB] = lB;
            }
        }
    }
    __syncthreads();

    // softmax in log2 domain: logits are xL, so 2^(l - m) = e^(orig - m')
    for (int q = 0; q < 8; ++q) {
        const int r = w * 8 + q;
        const float4 v = *(const float4*)&lg[r * 256 + lane * 4];
        float m = fmaxf(fmaxf(v.x, v.y), fmaxf(v.z, v.w));
        #pragma unroll
        for (int off = 32; off > 0; off >>= 1) m = fmaxf(m, __shfl_xor(m, off, 64));
        const float e0 = __builtin_amdgcn_exp2f(v.x - m);
        const float e1 = __builtin_amdgcn_exp2f(v.y - m);
        const float e2 = __builtin_amdgcn_exp2f(v.z - m);
        const float e3 = __builtin_amdgcn_exp2f(v.w - m);
        float s = e0 + e1 + e2 + e3;
        #pragma unroll
        for (int off = 32; off > 0; off >>= 1) s += __shfl_xor(s, off, 64);
        const float inv = 1.0f / s;
        float4 o4; o4.x = e0 * inv; o4.y = e1 * inv; o4.z = e2 * inv; o4.w = e3 * inv;
        *(float4*)&out[(rowbase + r) * kU + lane * 4] = o4;
    }
}

extern "C" void kernel_launch(void* const* d_in, const int* in_sizes, int n_in,
                              void* d_out, int out_size, void* d_ws, size_t ws_size,
                              hipStream_t stream) {
    const int*   z  = (const int*)d_in[0];
    const float* hW = (const float*)d_in[1];
    const float* hU = (const float*)d_in[2];
    const float* hb = (const float*)d_in[3];
    const float* fW = (const float*)d_in[4];
    const float* fb = (const float*)d_in[5];
    const float* iW = (const float*)d_in[6];
    const float* ib = (const float*)d_in[7];
    const float* cW = (const float*)d_in[8];
    const float* cb = (const float*)d_in[9];
    const float* oW = (const float*)d_in[10];
    const float* ob = (const float*)d_in[11];
    const float* tW = (const float*)d_in[12];
    const float* tb = (const float*)d_in[13];
    const float* yW = (const float*)d_in[14];
    const float* yb = (const float*)d_in[15];
    const float* h0 = (const float*)d_in[16];
    float* out = (float*)d_out;

    uint4* wfrag = (uint4*)d_ws;                         // 7*8192 uint4 = 896 KB
    float* embT  = (float*)((char*)d_ws + 7 * 8192 * 16); // 257*256 f32 = 257 KB

    hipFuncSetAttribute((const void*)rnn_phase1,
                        hipFuncAttributeMaxDynamicSharedMemorySize, 147456);
    hipFuncSetAttribute((const void*)rnn_phase2,
                        hipFuncAttributeMaxDynamicSharedMemorySize, 81920);

    convert_frag<<<dim3(7 * 8192 / 256), dim3(256), 0, stream>>>(
        hU, fW, iW, cW, oW, tW, yW, wfrag);
    convert_emb<<<dim3(257), dim3(256), 0, stream>>>(hW, hb, embT);
    rnn_phase1<<<dim3(kB / 16), dim3(512), 147456, stream>>>(
        z, embT, fb, ib, cb, h0, wfrag, (unsigned*)out);
    rnn_phase2<<<dim3((kB * kS) / 32), dim3(256), 81920, stream>>>(
        ob, tb, yb, wfrag, out);
}